// Round 9
// baseline (2117.815 us; speedup 1.0000x reference)
//
#include <hip/hip_runtime.h>

typedef unsigned short ushort_t;
typedef unsigned int uint_t;
typedef __attribute__((ext_vector_type(8))) short short8v;
typedef __attribute__((ext_vector_type(4))) float floatx4;

__device__ __forceinline__ float b2f(ushort_t u) {
    unsigned int x = ((unsigned int)u) << 16;
    float f; __builtin_memcpy(&f, &x, 4); return f;
}
__device__ __forceinline__ float lo16f(uint_t v) {
    unsigned int x = v << 16; float f; __builtin_memcpy(&f, &x, 4); return f;
}
__device__ __forceinline__ float hi16f(uint_t v) {
    unsigned int x = v & 0xffff0000u; float f; __builtin_memcpy(&f, &x, 4); return f;
}
__device__ __forceinline__ ushort_t f2b(float f) {
    unsigned int x; __builtin_memcpy(&x, &f, 4);
    unsigned int lsb = (x >> 16) & 1u;
    x += 0x7fffu + lsb;
    return (ushort_t)(x >> 16);
}
__device__ __forceinline__ uint_t pack2(float a, float b) {
    return (uint_t)f2b(a) | ((uint_t)f2b(b) << 16);
}
__device__ __forceinline__ float leaky01(float v) { return v > 0.f ? v : 0.01f * v; }

// ---------------- CSR build ----------------
__global__ void init_k(int* cnt, int N) {
    int i = blockIdx.x * 256 + threadIdx.x;
    if (i < N) cnt[i] = 1;   // self-loop
}

__global__ void count_k(const int* __restrict__ ei, int* cnt, int* pos, int E) {
    int e = blockIdx.x * 256 + threadIdx.x;
    if (e < E) pos[e] = atomicAdd(&cnt[ei[E + e]], 1);
}

__launch_bounds__(1024)
__global__ void scan_k(const int* __restrict__ cnt, int* rp, int n) {
    __shared__ int wsum[16];
    int tid = threadIdx.x; int lane = tid & 63, wid = tid >> 6;
    int base = 0;
    for (int start = 0; start < n; start += 4096) {
        int v[4]; int s = 0;
        #pragma unroll
        for (int j = 0; j < 4; ++j) {
            int i = start + tid * 4 + j;
            v[j] = (i < n) ? cnt[i] : 0; s += v[j];
        }
        int sc = s;
        #pragma unroll
        for (int off = 1; off < 64; off <<= 1) {
            int t = __shfl_up(sc, off);
            if (lane >= off) sc += t;
        }
        if (lane == 63) wsum[wid] = sc;
        __syncthreads();
        if (wid == 0) {
            int ws = (lane < 16) ? wsum[lane] : 0;
            #pragma unroll
            for (int off = 1; off < 16; off <<= 1) {
                int t = __shfl_up(ws, off);
                if (lane >= off) ws += t;
            }
            if (lane < 16) wsum[lane] = ws;
        }
        __syncthreads();
        int wbase = (wid > 0) ? wsum[wid - 1] : 0;
        int excl = base + wbase + (sc - s);
        #pragma unroll
        for (int j = 0; j < 4; ++j) {
            int i = start + tid * 4 + j;
            if (i < n) rp[i] = excl;
            excl += v[j];
        }
        int total = wsum[15];
        __syncthreads();
        base += total;
    }
    if (tid == 0) rp[n] = base;
}

// packed edge record: low16 = src id, high16 = bf16 weight/coef
__global__ void post_k(const int* __restrict__ rp, uint_t* er, int N) {
    int i = blockIdx.x * 256 + threadIdx.x;
    if (i < N) er[rp[i]] = (uint_t)i | (0x3F80u << 16);   // w = 1.0 (bf16)
}

__global__ void scat_k(const int* __restrict__ ei, const float* __restrict__ ew,
                       const int* __restrict__ rp, const int* __restrict__ pos,
                       uint_t* er, int E) {
    int e = blockIdx.x * 256 + threadIdx.x;
    if (e < E) {
        int dst = ei[E + e];
        er[rp[dst] + pos[e]] = (uint_t)(ei[e] & 0xffff) | ((uint_t)f2b(ew[e]) << 16);
    }
}

// wave per node: dinv[i] = rsqrt(sum of segment weights)
__global__ void deg_k(const int* __restrict__ rp, const uint_t* __restrict__ er,
                      float* dinv, int N) {
    int wave = threadIdx.x >> 6, lane = threadIdx.x & 63;
    int node = blockIdx.x * 4 + wave;
    if (node >= N) return;
    int s0 = rp[node], end = rp[node + 1];
    float sum = 0.f;
    for (int s = s0 + lane; s < end; s += 64) sum += hi16f(er[s]);
    #pragma unroll
    for (int off = 32; off; off >>= 1) sum += __shfl_xor(sum, off);
    if (lane == 0) dinv[node] = rsqrtf(sum);
}

// wave per node: coef = dinv[src] * w * dinv[node], stored bf16 in high16
__global__ void coef_k(const int* __restrict__ rp, uint_t* er,
                       const float* __restrict__ dinv, int N) {
    int wave = threadIdx.x >> 6, lane = threadIdx.x & 63;
    int node = blockIdx.x * 4 + wave;
    if (node >= N) return;
    int s0 = rp[node], end = rp[node + 1];
    float dn = dinv[node];
    for (int s = s0 + lane; s < end; s += 64) {
        uint_t r = er[s];
        int src = r & 0xffffu;
        float cf = dinv[src] * hi16f(r) * dn;
        er[s] = (uint_t)src | ((uint_t)f2b(cf) << 16);
    }
}

// ---------------- weight prep: transpose + cast to bf16 ----------------
__global__ void prep_w(const float* __restrict__ gcn_W, const float* __restrict__ gat_W,
                       const float* __restrict__ Win, ushort_t* __restrict__ wt,
                       ushort_t* __restrict__ wtin) {
    int idx = blockIdx.x * 256 + threadIdx.x;
    if (idx < 10 * 16384) {
        int l = idx >> 14, r = idx & 16383;
        int n = r >> 7, k = r & 127;
        const float* src = (l < 5) ? (gcn_W + l * 16384) : (gat_W + (l - 5) * 16384);
        wt[idx] = f2b(src[k * 128 + n]);
    } else {
        int idx2 = idx - 10 * 16384;
        if (idx2 < 128 * 320) {
            int n = idx2 / 320, k = idx2 - n * 320;
            wtin[idx2] = f2b(k < 300 ? Win[k * 128 + n] : 0.f);
        }
    }
}

// ---------------- cat projection: cp[400][128] = cat_emb @ Win[300:400] ----------------
__global__ void cat_proj_k(const float* __restrict__ ce, const float* __restrict__ Win,
                           float* __restrict__ cp) {
    __shared__ float row[100];
    int r = blockIdx.x, tid = threadIdx.x;   // 128 threads
    if (tid < 100) row[tid] = ce[r * 100 + tid];
    __syncthreads();
    float acc = 0.f;
    #pragma unroll 4
    for (int k = 0; k < 100; ++k) acc += row[k] * Win[(300 + k) * 128 + tid];
    cp[r * 128 + tid] = acc;
}

// ---------------- poi projection: pp[POI_LEN][128] bf16 = poi_emb @ Win[0:300] (MFMA) ---
__launch_bounds__(256)
__global__ void poi_gemm(const float* __restrict__ pe, const ushort_t* __restrict__ wtin,
                         ushort_t* __restrict__ pp, int P) {
    __shared__ __align__(16) ushort_t As[64 * 328];
    int tid = threadIdx.x;
    int wid = tid >> 6, lane = tid & 63;
    int r0 = blockIdx.x * 64;
    #pragma unroll
    for (int p = 0; p < 19; ++p) {
        int idx = tid + p * 256;              // need 4800 = 64 rows * 75 f4
        if (idx < 4800) {
            int row = idx / 75, kq = idx - row * 75;
            int grow = r0 + row;
            float4 v = make_float4(0.f, 0.f, 0.f, 0.f);
            if (grow < P) v = *(const float4*)&pe[(size_t)grow * 300 + kq * 4];
            ushort4 b;
            b.x = f2b(v.x); b.y = f2b(v.y); b.z = f2b(v.z); b.w = f2b(v.w);
            *(ushort4*)&As[row * 328 + kq * 4] = b;
        }
    }
    #pragma unroll
    for (int p = 0; p < 5; ++p) {
        int idx = tid + p * 256;              // 1280 = 64 rows * 20 pad cols
        if (idx < 1280) {
            int row = idx / 20, j = idx - row * 20;
            As[row * 328 + 300 + j] = 0;
        }
    }
    __syncthreads();
    int m = lane & 15, q = lane >> 4;
    short8v af[10];
    #pragma unroll
    for (int kc = 0; kc < 10; ++kc)
        af[kc] = *(const short8v*)&As[(wid * 16 + m) * 328 + kc * 32 + q * 8];
    #pragma unroll
    for (int ct = 0; ct < 8; ++ct) {
        const ushort_t* wr = wtin + (size_t)(ct * 16 + m) * 320 + q * 8;
        floatx4 acc = {0.f, 0.f, 0.f, 0.f};
        #pragma unroll
        for (int kc = 0; kc < 10; ++kc) {
            short8v b = *(const short8v*)(wr + kc * 32);
            acc = __builtin_amdgcn_mfma_f32_16x16x32_bf16(af[kc], b, acc, 0, 0, 0);
        }
        int col = ct * 16 + m;
        #pragma unroll
        for (int rg = 0; rg < 4; ++rg) {
            int row = r0 + wid * 16 + q * 4 + rg;
            if (row < P) pp[(size_t)row * 128 + col] = f2b(acc[rg]);
        }
    }
}

// ---------------- fused layer GEMM (MFMA), bf16 state ----------------
// NORM: while staging, xb += leaky(graphnorm(gb)) (in place, bf16), A = xb_new
// ALAR: epilogue computes al/ar = xw_row . asrc/adst
template <int NORM, int ALAR>
__launch_bounds__(256)
__global__ void gemm_fused(ushort_t* __restrict__ xb, const ushort_t* __restrict__ gb,
                           const float* __restrict__ mom,
                           const float* __restrict__ gamma, const float* __restrict__ beta,
                           const float* __restrict__ alpha,
                           const ushort_t* __restrict__ wt,
                           const float* __restrict__ asrc, const float* __restrict__ adst,
                           ushort_t* __restrict__ xw,
                           float* __restrict__ al, float* __restrict__ ar, int N) {
    __shared__ __align__(16) ushort_t As[64 * 136];
    __shared__ float sc[128], sh[128];
    int tid = threadIdx.x;
    if (NORM) {
        if (tid < 128) {
            float mmean = mom[tid] / (float)N;
            float a = alpha[tid];
            float var = mom[128 + tid] / (float)N - 2.f * a * mmean * mmean + a * a * mmean * mmean;
            float s = gamma[tid] * rsqrtf(var + 1e-5f);
            sc[tid] = s;
            sh[tid] = beta[tid] - s * a * mmean;
        }
        __syncthreads();
    }
    int r0 = blockIdx.x * 64;
    #pragma unroll
    for (int p = 0; p < 4; ++p) {
        int idx = tid + p * 256;          // 0..1023, each 8 bf16 (16B)
        int row = idx >> 4, c8 = (idx & 15) * 8;
        int grow = r0 + row;
        uint4 xv = make_uint4(0u, 0u, 0u, 0u);
        if (grow < N) {
            size_t base = (size_t)grow * 128 + c8;
            xv = *(const uint4*)&xb[base];
            if (NORM) {
                uint4 gv = *(const uint4*)&gb[base];
                float xf[8] = {lo16f(xv.x), hi16f(xv.x), lo16f(xv.y), hi16f(xv.y),
                               lo16f(xv.z), hi16f(xv.z), lo16f(xv.w), hi16f(xv.w)};
                float gf[8] = {lo16f(gv.x), hi16f(gv.x), lo16f(gv.y), hi16f(gv.y),
                               lo16f(gv.z), hi16f(gv.z), lo16f(gv.w), hi16f(gv.w)};
                #pragma unroll
                for (int j = 0; j < 8; ++j)
                    xf[j] += leaky01(sc[c8 + j] * gf[j] + sh[c8 + j]);
                xv.x = pack2(xf[0], xf[1]); xv.y = pack2(xf[2], xf[3]);
                xv.z = pack2(xf[4], xf[5]); xv.w = pack2(xf[6], xf[7]);
                *(uint4*)&xb[base] = xv;
            }
        }
        *(uint4*)&As[row * 136 + c8] = xv;
    }
    __syncthreads();
    int wid = tid >> 6, lane = tid & 63;
    int m = lane & 15, q = lane >> 4;
    const int arr = (wid * 16 + m) * 136 + q * 8;
    short8v a0 = *(const short8v*)&As[arr];
    short8v a1 = *(const short8v*)&As[arr + 32];
    short8v a2 = *(const short8v*)&As[arr + 64];
    short8v a3 = *(const short8v*)&As[arr + 96];
    float alsum[4] = {0.f, 0.f, 0.f, 0.f}, arsum[4] = {0.f, 0.f, 0.f, 0.f};
    #pragma unroll
    for (int ct = 0; ct < 8; ++ct) {
        const ushort_t* wr = wt + (size_t)(ct * 16 + m) * 128 + q * 8;
        short8v b0 = *(const short8v*)(wr);
        short8v b1 = *(const short8v*)(wr + 32);
        short8v b2 = *(const short8v*)(wr + 64);
        short8v b3 = *(const short8v*)(wr + 96);
        floatx4 acc = {0.f, 0.f, 0.f, 0.f};
        acc = __builtin_amdgcn_mfma_f32_16x16x32_bf16(a0, b0, acc, 0, 0, 0);
        acc = __builtin_amdgcn_mfma_f32_16x16x32_bf16(a1, b1, acc, 0, 0, 0);
        acc = __builtin_amdgcn_mfma_f32_16x16x32_bf16(a2, b2, acc, 0, 0, 0);
        acc = __builtin_amdgcn_mfma_f32_16x16x32_bf16(a3, b3, acc, 0, 0, 0);
        int col = ct * 16 + m;
        if (ALAR) {
            float av = asrc[col], dv = adst[col];
            #pragma unroll
            for (int rg = 0; rg < 4; ++rg) {
                alsum[rg] += acc[rg] * av;
                arsum[rg] += acc[rg] * dv;
            }
        }
        #pragma unroll
        for (int rg = 0; rg < 4; ++rg) {
            int row = r0 + wid * 16 + q * 4 + rg;
            if (row < N) xw[(size_t)row * 128 + col] = f2b(acc[rg]);
        }
    }
    if (ALAR) {
        #pragma unroll
        for (int rg = 0; rg < 4; ++rg) {
            #pragma unroll
            for (int off = 1; off < 16; off <<= 1) {
                alsum[rg] += __shfl_xor(alsum[rg], off);
                arsum[rg] += __shfl_xor(arsum[rg], off);
            }
        }
        if (m == 0) {
            #pragma unroll
            for (int rg = 0; rg < 4; ++rg) {
                int row = r0 + wid * 16 + q * 4 + rg;
                if (row < N) { al[row] = alsum[rg]; ar[row] = arsum[rg]; }
            }
        }
    }
}

// ---------------- combine: xw0 = pp[poi_id] + cp[cat_id] + feat3 @ Win[400:403] --------
__global__ void combine_k(const ushort_t* __restrict__ pp, const float* __restrict__ cp,
                          const int* __restrict__ poi_ids, const int* __restrict__ cat_ids,
                          const float* __restrict__ feat3, const float* __restrict__ Win,
                          ushort_t* __restrict__ xw, int N) {
    __shared__ float wf0[128], wf1[128], wf2[128];
    int tid = threadIdx.x;
    if (tid < 128) {
        wf0[tid] = Win[400 * 128 + tid];
        wf1[tid] = Win[401 * 128 + tid];
        wf2[tid] = Win[402 * 128 + tid];
    }
    __syncthreads();
    int node = blockIdx.x * 2 + (tid >> 7);
    int c = tid & 127;
    if (node >= N) return;
    int pid = poi_ids[node], cid = cat_ids[node];
    float f0 = feat3[node * 3], f1 = feat3[node * 3 + 1], f2 = feat3[node * 3 + 2];
    float v = b2f(pp[(size_t)pid * 128 + c]) + cp[cid * 128 + c]
            + f0 * wf0[c] + f1 * wf1[c] + f2 * wf2[c];
    xw[(size_t)node * 128 + c] = f2b(v);
}

// ---------------- aggregation ----------------
// one wave per node; lane covers 8 channels (16B), 4 edge-subslots;
// cascaded unroll: stride-32 -> stride-16 -> stride-4. Output g in bf16.
// MODE 0: GCN (coef = rec high16).  MODE 1: + fused leaky (input layer, writes xb).
// MODE 2: GAT softmax over al[src]+ar[node] (online m,d prepass).
template <int MODE>
__launch_bounds__(256)
__global__ void agg_k(const ushort_t* __restrict__ xw, const int* __restrict__ rp,
                      const uint_t* __restrict__ er,
                      const float* __restrict__ al, const float* __restrict__ ar,
                      const float* __restrict__ bias, ushort_t* __restrict__ gout, int N) {
    int wave = threadIdx.x >> 6, lane = threadIdx.x & 63;
    int node = blockIdx.x * 4 + wave;
    if (node >= N) return;
    int s0 = __builtin_amdgcn_readfirstlane(rp[node]);
    int end = __builtin_amdgcn_readfirstlane(rp[node + 1]);
    int g8 = lane >> 4;          // edge subslot 0..3
    int c8 = (lane & 15) * 8;    // channel base
    float mmax = 0.f, inv = 0.f, ari = 0.f;
    if (MODE == 2) {
        ari = ar[node];
        float mm = -1e30f, ds = 0.f;
        for (int s = s0 + lane; s < end; s += 64) {
            int src = er[s] & 0xffffu;
            float e = al[src] + ari; e = e > 0.f ? e : 0.2f * e;
            if (e > mm) { ds = ds * __expf(mm - e) + 1.f; mm = e; }
            else ds += __expf(e - mm);
        }
        #pragma unroll
        for (int off = 32; off; off >>= 1) {
            float mo = __shfl_xor(mm, off);
            float dso = __shfl_xor(ds, off);
            float mn = fmaxf(mm, mo);
            ds = ds * __expf(mm - mn) + dso * __expf(mo - mn);
            mm = mn;
        }
        mmax = mm;
        inv = 1.f / ds;
    }
    float acc[8] = {0.f, 0.f, 0.f, 0.f, 0.f, 0.f, 0.f, 0.f};
    auto body = [&](int e) {
        uint_t r = er[e];
        int src = r & 0xffffu;
        float cf;
        if (MODE == 2) {
            float ev = al[src] + ari; ev = ev > 0.f ? ev : 0.2f * ev;
            cf = __expf(ev - mmax) * inv;
        } else {
            cf = hi16f(r);
        }
        uint4 u = *(const uint4*)&xw[(size_t)src * 128 + c8];
        acc[0] += cf * lo16f(u.x); acc[1] += cf * hi16f(u.x);
        acc[2] += cf * lo16f(u.y); acc[3] += cf * hi16f(u.y);
        acc[4] += cf * lo16f(u.z); acc[5] += cf * hi16f(u.z);
        acc[6] += cf * lo16f(u.w); acc[7] += cf * hi16f(u.w);
    };
    int e = s0 + g8;
    for (; e + 28 < end; e += 32) {
        body(e);      body(e + 4);  body(e + 8);  body(e + 12);
        body(e + 16); body(e + 20); body(e + 24); body(e + 28);
    }
    for (; e + 12 < end; e += 16) {
        body(e); body(e + 4); body(e + 8); body(e + 12);
    }
    for (; e < end; e += 4) body(e);
    #pragma unroll
    for (int k = 0; k < 8; ++k) {
        acc[k] += __shfl_xor(acc[k], 16);
        acc[k] += __shfl_xor(acc[k], 32);
    }
    if (g8 == 0) {
        float v[8];
        #pragma unroll
        for (int k = 0; k < 8; ++k) {
            v[k] = acc[k] + bias[c8 + k];
            if (MODE == 1) v[k] = leaky01(v[k]);
        }
        uint4 o;
        o.x = pack2(v[0], v[1]); o.y = pack2(v[2], v[3]);
        o.z = pack2(v[4], v[5]); o.w = pack2(v[6], v[7]);
        *(uint4*)&gout[(size_t)node * 128 + c8] = o;
    }
}

// ---------------- GraphNorm moments (bf16 streaming) ----------------
__global__ void moments_k(const ushort_t* __restrict__ g, float* mom, int n16) {
    __shared__ float s1s[256][8], s2s[256][8];
    int tid = threadIdx.x;
    long long T = (long long)gridDim.x * 256;
    float a1[8] = {0,0,0,0,0,0,0,0}, a2[8] = {0,0,0,0,0,0,0,0};
    const uint4* g4 = (const uint4*)g;
    for (long long idx = (long long)blockIdx.x * 256 + tid; idx < n16; idx += T) {
        uint4 u = g4[idx];
        float f[8] = {lo16f(u.x), hi16f(u.x), lo16f(u.y), hi16f(u.y),
                      lo16f(u.z), hi16f(u.z), lo16f(u.w), hi16f(u.w)};
        #pragma unroll
        for (int j = 0; j < 8; ++j) { a1[j] += f[j]; a2[j] += f[j] * f[j]; }
    }
    #pragma unroll
    for (int j = 0; j < 8; ++j) { s1s[tid][j] = a1[j]; s2s[tid][j] = a2[j]; }
    __syncthreads();
    if (tid < 32) {
        float r1[8] = {0,0,0,0,0,0,0,0}, r2[8] = {0,0,0,0,0,0,0,0};
        for (int t = tid; t < 256; t += 32) {
            #pragma unroll
            for (int j = 0; j < 8; ++j) { r1[j] += s1s[t][j]; r2[j] += s2s[t][j]; }
        }
        // channel of (t,j) = (8t+j)&127; constant over t for t = tid+32k
        #pragma unroll
        for (int j = 0; j < 8; ++j) {
            int ch = (8 * tid + j) & 127;
            atomicAdd(&mom[ch], r1[j]);
            atomicAdd(&mom[128 + ch], r2[j]);
        }
    }
}

// ---------------- final: x-update (not stored) + dot with Wout ----------------
__global__ void norm_ydot_k(const ushort_t* __restrict__ xb, const ushort_t* __restrict__ gb,
                            const float* __restrict__ mom,
                            const float* __restrict__ gamma, const float* __restrict__ beta,
                            const float* __restrict__ alpha, const float* __restrict__ Wout,
                            float* __restrict__ yv, int N) {
    __shared__ float sc[128], sh[128], wv[128];
    int tid = threadIdx.x;
    if (tid < 128) {
        float m = mom[tid] / (float)N;
        float a = alpha[tid];
        float var = mom[128 + tid] / (float)N - 2.f * a * m * m + a * a * m * m;
        float s = gamma[tid] * rsqrtf(var + 1e-5f);
        sc[tid] = s;
        sh[tid] = beta[tid] - s * a * m;
        wv[tid] = Wout[tid];
    }
    __syncthreads();
    int wave = tid >> 6, lane = tid & 63;
    int node = blockIdx.x * 4 + wave;
    if (node >= N) return;
    int c = lane * 2;
    uint_t gv = *(const uint_t*)&gb[(size_t)node * 128 + c];
    uint_t xv = *(const uint_t*)&xb[(size_t)node * 128 + c];
    float v0 = lo16f(xv) + leaky01(sc[c] * lo16f(gv) + sh[c]);
    float v1 = hi16f(xv) + leaky01(sc[c + 1] * hi16f(gv) + sh[c + 1]);
    float acc = v0 * wv[c] + v1 * wv[c + 1];
    #pragma unroll
    for (int off = 32; off; off >>= 1) acc += __shfl_xor(acc, off);
    if (lane == 0) yv[node] = acc;
}

// wave per node: xs = leaky( sum coef*yv[src] + b_out )
__global__ void aggs_k(const float* __restrict__ yv, const int* __restrict__ rp,
                       const uint_t* __restrict__ er,
                       const float* __restrict__ b_out, float* xs, int N) {
    int wave = threadIdx.x >> 6, lane = threadIdx.x & 63;
    int node = blockIdx.x * 4 + wave;
    if (node >= N) return;
    int s0 = rp[node], end = rp[node + 1];
    float acc = 0.f;
    for (int s = s0 + lane; s < end; s += 64) {
        uint_t r = er[s];
        acc += hi16f(r) * yv[r & 0xffffu];
    }
    #pragma unroll
    for (int off = 32; off; off >>= 1) acc += __shfl_xor(acc, off);
    if (lane == 0) xs[node] = leaky01(acc + b_out[0]);
}

__global__ void fc1_k(const float* __restrict__ xs, const float* __restrict__ W1,
                      float* hacc, int N) {
    __shared__ float sd[256];
    int tid = threadIdx.x;
    int j = tid & 127, half = tid >> 7;
    int r0 = blockIdx.x * 256;
    float acc = 0.f;
    for (int rr = half; rr < 256; rr += 2) {
        int r = r0 + rr;
        if (r < N) acc += xs[r] * W1[(size_t)r * 128 + j];
    }
    sd[tid] = acc;
    __syncthreads();
    if (tid < 128) atomicAdd(&hacc[tid], sd[tid] + sd[tid + 128]);
}

__global__ void fc2_k(const float* __restrict__ hacc, const float* __restrict__ b1,
                      const float* __restrict__ W2, const float* __restrict__ b2v,
                      float* out, int P) {
    __shared__ float hs[128];
    int tid = threadIdx.x;
    if (tid < 128) {
        float h = hacc[tid] + b1[tid];
        hs[tid] = h > 0.f ? h : 0.f;
    }
    __syncthreads();
    int p = blockIdx.x * 256 + tid;
    if (p >= P) return;
    float acc = 0.f;
    #pragma unroll 8
    for (int j = 0; j < 128; ++j) acc += hs[j] * W2[(size_t)j * P + p];
    acc += b2v[p];
    out[p] = acc > 0.f ? acc : 0.f;
}

// ---------------- launcher ----------------
extern "C" void kernel_launch(void* const* d_in, const int* in_sizes, int n_in,
                              void* d_out, int out_size, void* d_ws, size_t ws_size,
                              hipStream_t stream) {
    const int*   poi_ids  = (const int*)d_in[0];
    const int*   cat_ids  = (const int*)d_in[1];
    const float* feat3    = (const float*)d_in[2];
    const int*   ei       = (const int*)d_in[3];
    const float* ew       = (const float*)d_in[4];
    const float* poi_emb  = (const float*)d_in[5];
    const float* cat_emb  = (const float*)d_in[6];
    const float* Win      = (const float*)d_in[7];
    const float* b_in     = (const float*)d_in[8];
    const float* gcn_W    = (const float*)d_in[9];
    const float* gcn_b    = (const float*)d_in[10];
    const float* gn_gamma = (const float*)d_in[11];
    const float* gn_beta  = (const float*)d_in[12];
    const float* gn_alpha = (const float*)d_in[13];
    const float* gat_W    = (const float*)d_in[14];
    const float* gat_asrc = (const float*)d_in[15];
    const float* gat_adst = (const float*)d_in[16];
    const float* gat_b    = (const float*)d_in[17];
    const float* Wout     = (const float*)d_in[18];
    const float* b_out    = (const float*)d_in[19];
    const float* fc_W1    = (const float*)d_in[20];
    const float* fc_b1    = (const float*)d_in[21];
    const float* fc_W2    = (const float*)d_in[22];
    const float* fc_b2    = (const float*)d_in[23];

    const int N = in_sizes[0];
    const int E = in_sizes[4];
    const int POI = in_sizes[5] / 300;
    const int P = out_size;
    const int TOT = E + N;
    const int n128 = N * 128;
    const int n16 = n128 / 8;
    const int NPAD = ((N + 63) / 64) * 64;
    const int PPAD = ((POI + 63) / 64) * 64;

    // workspace carve (256B aligned)
    char* w = (char*)d_ws;
    size_t off = 0;
    auto take = [&](size_t bytes) -> char* {
        char* p = w + off;
        off = (off + bytes + 255) & ~(size_t)255;
        return p;
    };
    ushort_t* xb   = (ushort_t*)take((size_t)NPAD * 128 * 2);
    ushort_t* g    = (ushort_t*)take((size_t)NPAD * 128 * 2);
    ushort_t* xw   = (ushort_t*)take((size_t)NPAD * 128 * 2);
    ushort_t* pp   = (ushort_t*)take((size_t)PPAD * 128 * 2);
    float*    cp   = (float*)take((size_t)400 * 128 * 4);
    ushort_t* wt   = (ushort_t*)take((size_t)10 * 16384 * 2);
    ushort_t* wtin = (ushort_t*)take((size_t)128 * 320 * 2);
    int*    rp   = (int*)take((size_t)(N + 1) * 4);
    int*    cnt  = (int*)take((size_t)N * 4);
    int*    pos  = (int*)take((size_t)E * 4);
    float*  dinv = (float*)take((size_t)N * 4);
    uint_t* er   = (uint_t*)take((size_t)TOT * 4);
    float*  al   = (float*)take((size_t)N * 4);
    float*  ar   = (float*)take((size_t)N * 4);
    float*  yv   = (float*)take((size_t)N * 4);
    float*  xs   = (float*)take((size_t)N * 4);
    float*  mom  = (float*)take((size_t)(10 * 256 + 128) * 4);
    float*  hacc = mom + 10 * 256;

    const int gN   = (N + 255) / 256;
    const int gE   = (E + 255) / 256;
    const int gMM  = NPAD / 64;
    const int gPOI = PPAD / 64;
    const int gW   = (N + 3) / 4;
    const int gP   = (P + 255) / 256;

    hipMemsetAsync(mom, 0, (size_t)(10 * 256 + 128) * 4, stream);

    // CSR build
    init_k<<<gN, 256, 0, stream>>>(cnt, N);
    count_k<<<gE, 256, 0, stream>>>(ei, cnt, pos, E);
    scan_k<<<1, 1024, 0, stream>>>(cnt, rp, N);
    post_k<<<gN, 256, 0, stream>>>(rp, er, N);
    scat_k<<<gE, 256, 0, stream>>>(ei, ew, rp, pos, er, E);
    deg_k<<<gW, 256, 0, stream>>>(rp, er, dinv, N);
    coef_k<<<gW, 256, 0, stream>>>(rp, er, dinv, N);

    // weight prep + input conv
    prep_w<<<(10 * 16384 + 128 * 320 + 255) / 256, 256, 0, stream>>>(gcn_W, gat_W, Win, wt, wtin);
    cat_proj_k<<<400, 128, 0, stream>>>(cat_emb, Win, cp);
    poi_gemm<<<gPOI, 256, 0, stream>>>(poi_emb, wtin, pp, POI);
    combine_k<<<(N + 1) / 2, 256, 0, stream>>>(pp, cp, poi_ids, cat_ids, feat3, Win, xw, N);
    agg_k<1><<<gW, 256, 0, stream>>>(xw, rp, er, nullptr, nullptr, b_in, xb, N);

    // 5 GcnUnits
    for (int l = 0; l < 5; ++l) {
        // GCN half: gemm (fused norm of previous GAT half for l>=1)
        if (l == 0)
            gemm_fused<0, 0><<<gMM, 256, 0, stream>>>(xb, nullptr, nullptr, nullptr, nullptr,
                                                      nullptr, wt, nullptr, nullptr,
                                                      xw, nullptr, nullptr, N);
        else
            gemm_fused<1, 0><<<gMM, 256, 0, stream>>>(xb, g, mom + (2 * l - 1) * 256,
                                                      gn_gamma + (l - 1) * 128,
                                                      gn_beta + (l - 1) * 128,
                                                      gn_alpha + (l - 1) * 128,
                                                      wt + (size_t)l * 16384, nullptr, nullptr,
                                                      xw, nullptr, nullptr, N);
        agg_k<0><<<gW, 256, 0, stream>>>(xw, rp, er, nullptr, nullptr, gcn_b + l * 128, g, N);
        moments_k<<<240, 256, 0, stream>>>(g, mom + (2 * l) * 256, n16);

        // GAT half: gemm with fused norm (this unit's GCN) + alar epilogue
        gemm_fused<1, 1><<<gMM, 256, 0, stream>>>(xb, g, mom + (2 * l) * 256,
                                                  gn_gamma + l * 128, gn_beta + l * 128,
                                                  gn_alpha + l * 128,
                                                  wt + (size_t)(5 + l) * 16384,
                                                  gat_asrc + l * 128, gat_adst + l * 128,
                                                  xw, al, ar, N);
        agg_k<2><<<gW, 256, 0, stream>>>(xw, rp, er, al, ar, gat_b + l * 128, g, N);
        moments_k<<<240, 256, 0, stream>>>(g, mom + (2 * l + 1) * 256, n16);
    }

    // final norm + output conv (C -> 1) + leaky
    norm_ydot_k<<<gW, 256, 0, stream>>>(xb, g, mom + 9 * 256, gn_gamma + 4 * 128,
                                        gn_beta + 4 * 128, gn_alpha + 4 * 128, Wout, yv, N);
    aggs_k<<<gW, 256, 0, stream>>>(yv, rp, er, b_out, xs, N);

    // FC head
    fc1_k<<<(N + 255) / 256, 256, 0, stream>>>(xs, fc_W1, hacc, N);
    fc2_k<<<gP, 256, 0, stream>>>(hacc, fc_b1, fc_W2, fc_b2, (float*)d_out, P);
}

// Round 10
// 1271.225 us; speedup vs baseline: 1.6660x; 1.6660x over previous
//
#include <hip/hip_runtime.h>

typedef unsigned short ushort_t;
typedef unsigned int uint_t;
typedef __attribute__((ext_vector_type(8))) short short8v;
typedef __attribute__((ext_vector_type(4))) float floatx4;

__device__ __forceinline__ float b2f(ushort_t u) {
    unsigned int x = ((unsigned int)u) << 16;
    float f; __builtin_memcpy(&f, &x, 4); return f;
}
__device__ __forceinline__ float lo16f(uint_t v) {
    unsigned int x = v << 16; float f; __builtin_memcpy(&f, &x, 4); return f;
}
__device__ __forceinline__ float hi16f(uint_t v) {
    unsigned int x = v & 0xffff0000u; float f; __builtin_memcpy(&f, &x, 4); return f;
}
__device__ __forceinline__ ushort_t f2b(float f) {
    unsigned int x; __builtin_memcpy(&x, &f, 4);
    unsigned int lsb = (x >> 16) & 1u;
    x += 0x7fffu + lsb;
    return (ushort_t)(x >> 16);
}
__device__ __forceinline__ uint_t pack2(float a, float b) {
    return (uint_t)f2b(a) | ((uint_t)f2b(b) << 16);
}
__device__ __forceinline__ float leaky01(float v) { return v > 0.f ? v : 0.01f * v; }

#define MOMB 240   // moments stage-1 blocks

// ---------------- CSR build ----------------
__global__ void init_k(int* cnt, int N) {
    int i = blockIdx.x * 256 + threadIdx.x;
    if (i < N) cnt[i] = 1;   // self-loop
}

__global__ void count_k(const int* __restrict__ ei, int* cnt, int* pos, int E) {
    int e = blockIdx.x * 256 + threadIdx.x;
    if (e < E) pos[e] = atomicAdd(&cnt[ei[E + e]], 1);
}

__launch_bounds__(1024)
__global__ void scan_k(const int* __restrict__ cnt, int* rp, int n) {
    __shared__ int wsum[16];
    int tid = threadIdx.x; int lane = tid & 63, wid = tid >> 6;
    int base = 0;
    for (int start = 0; start < n; start += 4096) {
        int v[4]; int s = 0;
        #pragma unroll
        for (int j = 0; j < 4; ++j) {
            int i = start + tid * 4 + j;
            v[j] = (i < n) ? cnt[i] : 0; s += v[j];
        }
        int sc = s;
        #pragma unroll
        for (int off = 1; off < 64; off <<= 1) {
            int t = __shfl_up(sc, off);
            if (lane >= off) sc += t;
        }
        if (lane == 63) wsum[wid] = sc;
        __syncthreads();
        if (wid == 0) {
            int ws = (lane < 16) ? wsum[lane] : 0;
            #pragma unroll
            for (int off = 1; off < 16; off <<= 1) {
                int t = __shfl_up(ws, off);
                if (lane >= off) ws += t;
            }
            if (lane < 16) wsum[lane] = ws;
        }
        __syncthreads();
        int wbase = (wid > 0) ? wsum[wid - 1] : 0;
        int excl = base + wbase + (sc - s);
        #pragma unroll
        for (int j = 0; j < 4; ++j) {
            int i = start + tid * 4 + j;
            if (i < n) rp[i] = excl;
            excl += v[j];
        }
        int total = wsum[15];
        __syncthreads();
        base += total;
    }
    if (tid == 0) rp[n] = base;
}

// packed edge record: low16 = src id, high16 = bf16 weight/coef
__global__ void post_k(const int* __restrict__ rp, uint_t* er, int N) {
    int i = blockIdx.x * 256 + threadIdx.x;
    if (i < N) er[rp[i]] = (uint_t)i | (0x3F80u << 16);   // w = 1.0 (bf16)
}

__global__ void scat_k(const int* __restrict__ ei, const float* __restrict__ ew,
                       const int* __restrict__ rp, const int* __restrict__ pos,
                       uint_t* er, int E) {
    int e = blockIdx.x * 256 + threadIdx.x;
    if (e < E) {
        int dst = ei[E + e];
        er[rp[dst] + pos[e]] = (uint_t)(ei[e] & 0xffff) | ((uint_t)f2b(ew[e]) << 16);
    }
}

// wave per node: dinv[i] = rsqrt(sum of segment weights)
__global__ void deg_k(const int* __restrict__ rp, const uint_t* __restrict__ er,
                      float* dinv, int N) {
    int wave = threadIdx.x >> 6, lane = threadIdx.x & 63;
    int node = blockIdx.x * 4 + wave;
    if (node >= N) return;
    int s0 = rp[node], end = rp[node + 1];
    float sum = 0.f;
    for (int s = s0 + lane; s < end; s += 64) sum += hi16f(er[s]);
    #pragma unroll
    for (int off = 32; off; off >>= 1) sum += __shfl_xor(sum, off);
    if (lane == 0) dinv[node] = rsqrtf(sum);
}

// wave per node: coef = dinv[src] * w * dinv[node], stored bf16 in high16
__global__ void coef_k(const int* __restrict__ rp, uint_t* er,
                       const float* __restrict__ dinv, int N) {
    int wave = threadIdx.x >> 6, lane = threadIdx.x & 63;
    int node = blockIdx.x * 4 + wave;
    if (node >= N) return;
    int s0 = rp[node], end = rp[node + 1];
    float dn = dinv[node];
    for (int s = s0 + lane; s < end; s += 64) {
        uint_t r = er[s];
        int src = r & 0xffffu;
        float cf = dinv[src] * hi16f(r) * dn;
        er[s] = (uint_t)src | ((uint_t)f2b(cf) << 16);
    }
}

// ---------------- weight prep: transpose + cast to bf16 ----------------
__global__ void prep_w(const float* __restrict__ gcn_W, const float* __restrict__ gat_W,
                       const float* __restrict__ Win, ushort_t* __restrict__ wt,
                       ushort_t* __restrict__ wtin) {
    int idx = blockIdx.x * 256 + threadIdx.x;
    if (idx < 10 * 16384) {
        int l = idx >> 14, r = idx & 16383;
        int n = r >> 7, k = r & 127;
        const float* src = (l < 5) ? (gcn_W + l * 16384) : (gat_W + (l - 5) * 16384);
        wt[idx] = f2b(src[k * 128 + n]);
    } else {
        int idx2 = idx - 10 * 16384;
        if (idx2 < 128 * 320) {
            int n = idx2 / 320, k = idx2 - n * 320;
            wtin[idx2] = f2b(k < 300 ? Win[k * 128 + n] : 0.f);
        }
    }
}

// ---------------- cat projection: cp[400][128] = cat_emb @ Win[300:400] ----------------
__global__ void cat_proj_k(const float* __restrict__ ce, const float* __restrict__ Win,
                           float* __restrict__ cp) {
    __shared__ float row[100];
    int r = blockIdx.x, tid = threadIdx.x;   // 128 threads
    if (tid < 100) row[tid] = ce[r * 100 + tid];
    __syncthreads();
    float acc = 0.f;
    #pragma unroll 4
    for (int k = 0; k < 100; ++k) acc += row[k] * Win[(300 + k) * 128 + tid];
    cp[r * 128 + tid] = acc;
}

// ---------------- poi projection: pp[POI_LEN][128] bf16 = poi_emb @ Win[0:300] (MFMA) ---
__launch_bounds__(256)
__global__ void poi_gemm(const float* __restrict__ pe, const ushort_t* __restrict__ wtin,
                         ushort_t* __restrict__ pp, int P) {
    __shared__ __align__(16) ushort_t As[64 * 328];
    int tid = threadIdx.x;
    int wid = tid >> 6, lane = tid & 63;
    int r0 = blockIdx.x * 64;
    #pragma unroll
    for (int p = 0; p < 19; ++p) {
        int idx = tid + p * 256;              // need 4800 = 64 rows * 75 f4
        if (idx < 4800) {
            int row = idx / 75, kq = idx - row * 75;
            int grow = r0 + row;
            float4 v = make_float4(0.f, 0.f, 0.f, 0.f);
            if (grow < P) v = *(const float4*)&pe[(size_t)grow * 300 + kq * 4];
            ushort4 b;
            b.x = f2b(v.x); b.y = f2b(v.y); b.z = f2b(v.z); b.w = f2b(v.w);
            *(ushort4*)&As[row * 328 + kq * 4] = b;
        }
    }
    #pragma unroll
    for (int p = 0; p < 5; ++p) {
        int idx = tid + p * 256;              // 1280 = 64 rows * 20 pad cols
        if (idx < 1280) {
            int row = idx / 20, j = idx - row * 20;
            As[row * 328 + 300 + j] = 0;
        }
    }
    __syncthreads();
    int m = lane & 15, q = lane >> 4;
    short8v af[10];
    #pragma unroll
    for (int kc = 0; kc < 10; ++kc)
        af[kc] = *(const short8v*)&As[(wid * 16 + m) * 328 + kc * 32 + q * 8];
    #pragma unroll
    for (int ct = 0; ct < 8; ++ct) {
        const ushort_t* wr = wtin + (size_t)(ct * 16 + m) * 320 + q * 8;
        floatx4 acc = {0.f, 0.f, 0.f, 0.f};
        #pragma unroll
        for (int kc = 0; kc < 10; ++kc) {
            short8v b = *(const short8v*)(wr + kc * 32);
            acc = __builtin_amdgcn_mfma_f32_16x16x32_bf16(af[kc], b, acc, 0, 0, 0);
        }
        int col = ct * 16 + m;
        #pragma unroll
        for (int rg = 0; rg < 4; ++rg) {
            int row = r0 + wid * 16 + q * 4 + rg;
            if (row < P) pp[(size_t)row * 128 + col] = f2b(acc[rg]);
        }
    }
}

// ---------------- fused layer GEMM (MFMA), bf16 state ----------------
template <int NORM, int ALAR>
__launch_bounds__(256)
__global__ void gemm_fused(ushort_t* __restrict__ xb, const ushort_t* __restrict__ gb,
                           const float* __restrict__ mom,
                           const float* __restrict__ gamma, const float* __restrict__ beta,
                           const float* __restrict__ alpha,
                           const ushort_t* __restrict__ wt,
                           const float* __restrict__ asrc, const float* __restrict__ adst,
                           ushort_t* __restrict__ xw,
                           float* __restrict__ al, float* __restrict__ ar, int N) {
    __shared__ __align__(16) ushort_t As[64 * 136];
    __shared__ float sc[128], sh[128];
    int tid = threadIdx.x;
    if (NORM) {
        if (tid < 128) {
            float mmean = mom[tid] / (float)N;
            float a = alpha[tid];
            float var = mom[128 + tid] / (float)N - 2.f * a * mmean * mmean + a * a * mmean * mmean;
            float s = gamma[tid] * rsqrtf(var + 1e-5f);
            sc[tid] = s;
            sh[tid] = beta[tid] - s * a * mmean;
        }
        __syncthreads();
    }
    int r0 = blockIdx.x * 64;
    #pragma unroll
    for (int p = 0; p < 4; ++p) {
        int idx = tid + p * 256;          // 0..1023, each 8 bf16 (16B)
        int row = idx >> 4, c8 = (idx & 15) * 8;
        int grow = r0 + row;
        uint4 xv = make_uint4(0u, 0u, 0u, 0u);
        if (grow < N) {
            size_t base = (size_t)grow * 128 + c8;
            xv = *(const uint4*)&xb[base];
            if (NORM) {
                uint4 gv = *(const uint4*)&gb[base];
                float xf[8] = {lo16f(xv.x), hi16f(xv.x), lo16f(xv.y), hi16f(xv.y),
                               lo16f(xv.z), hi16f(xv.z), lo16f(xv.w), hi16f(xv.w)};
                float gf[8] = {lo16f(gv.x), hi16f(gv.x), lo16f(gv.y), hi16f(gv.y),
                               lo16f(gv.z), hi16f(gv.z), lo16f(gv.w), hi16f(gv.w)};
                #pragma unroll
                for (int j = 0; j < 8; ++j)
                    xf[j] += leaky01(sc[c8 + j] * gf[j] + sh[c8 + j]);
                xv.x = pack2(xf[0], xf[1]); xv.y = pack2(xf[2], xf[3]);
                xv.z = pack2(xf[4], xf[5]); xv.w = pack2(xf[6], xf[7]);
                *(uint4*)&xb[base] = xv;
            }
        }
        *(uint4*)&As[row * 136 + c8] = xv;
    }
    __syncthreads();
    int wid = tid >> 6, lane = tid & 63;
    int m = lane & 15, q = lane >> 4;
    const int arr = (wid * 16 + m) * 136 + q * 8;
    short8v a0 = *(const short8v*)&As[arr];
    short8v a1 = *(const short8v*)&As[arr + 32];
    short8v a2 = *(const short8v*)&As[arr + 64];
    short8v a3 = *(const short8v*)&As[arr + 96];
    float alsum[4] = {0.f, 0.f, 0.f, 0.f}, arsum[4] = {0.f, 0.f, 0.f, 0.f};
    #pragma unroll
    for (int ct = 0; ct < 8; ++ct) {
        const ushort_t* wr = wt + (size_t)(ct * 16 + m) * 128 + q * 8;
        short8v b0 = *(const short8v*)(wr);
        short8v b1 = *(const short8v*)(wr + 32);
        short8v b2 = *(const short8v*)(wr + 64);
        short8v b3 = *(const short8v*)(wr + 96);
        floatx4 acc = {0.f, 0.f, 0.f, 0.f};
        acc = __builtin_amdgcn_mfma_f32_16x16x32_bf16(a0, b0, acc, 0, 0, 0);
        acc = __builtin_amdgcn_mfma_f32_16x16x32_bf16(a1, b1, acc, 0, 0, 0);
        acc = __builtin_amdgcn_mfma_f32_16x16x32_bf16(a2, b2, acc, 0, 0, 0);
        acc = __builtin_amdgcn_mfma_f32_16x16x32_bf16(a3, b3, acc, 0, 0, 0);
        int col = ct * 16 + m;
        if (ALAR) {
            float av = asrc[col], dv = adst[col];
            #pragma unroll
            for (int rg = 0; rg < 4; ++rg) {
                alsum[rg] += acc[rg] * av;
                arsum[rg] += acc[rg] * dv;
            }
        }
        #pragma unroll
        for (int rg = 0; rg < 4; ++rg) {
            int row = r0 + wid * 16 + q * 4 + rg;
            if (row < N) xw[(size_t)row * 128 + col] = f2b(acc[rg]);
        }
    }
    if (ALAR) {
        #pragma unroll
        for (int rg = 0; rg < 4; ++rg) {
            #pragma unroll
            for (int off = 1; off < 16; off <<= 1) {
                alsum[rg] += __shfl_xor(alsum[rg], off);
                arsum[rg] += __shfl_xor(arsum[rg], off);
            }
        }
        if (m == 0) {
            #pragma unroll
            for (int rg = 0; rg < 4; ++rg) {
                int row = r0 + wid * 16 + q * 4 + rg;
                if (row < N) { al[row] = alsum[rg]; ar[row] = arsum[rg]; }
            }
        }
    }
}

// ---------------- combine: xw0 = pp[poi_id] + cp[cat_id] + feat3 @ Win[400:403] --------
__global__ void combine_k(const ushort_t* __restrict__ pp, const float* __restrict__ cp,
                          const int* __restrict__ poi_ids, const int* __restrict__ cat_ids,
                          const float* __restrict__ feat3, const float* __restrict__ Win,
                          ushort_t* __restrict__ xw, int N) {
    __shared__ float wf0[128], wf1[128], wf2[128];
    int tid = threadIdx.x;
    if (tid < 128) {
        wf0[tid] = Win[400 * 128 + tid];
        wf1[tid] = Win[401 * 128 + tid];
        wf2[tid] = Win[402 * 128 + tid];
    }
    __syncthreads();
    int node = blockIdx.x * 2 + (tid >> 7);
    int c = tid & 127;
    if (node >= N) return;
    int pid = poi_ids[node], cid = cat_ids[node];
    float f0 = feat3[node * 3], f1 = feat3[node * 3 + 1], f2 = feat3[node * 3 + 2];
    float v = b2f(pp[(size_t)pid * 128 + c]) + cp[cid * 128 + c]
            + f0 * wf0[c] + f1 * wf1[c] + f2 * wf2[c];
    xw[(size_t)node * 128 + c] = f2b(v);
}

// ---------------- aggregation ----------------
template <int MODE>
__launch_bounds__(256)
__global__ void agg_k(const ushort_t* __restrict__ xw, const int* __restrict__ rp,
                      const uint_t* __restrict__ er,
                      const float* __restrict__ al, const float* __restrict__ ar,
                      const float* __restrict__ bias, ushort_t* __restrict__ gout, int N) {
    int wave = threadIdx.x >> 6, lane = threadIdx.x & 63;
    int node = blockIdx.x * 4 + wave;
    if (node >= N) return;
    int s0 = __builtin_amdgcn_readfirstlane(rp[node]);
    int end = __builtin_amdgcn_readfirstlane(rp[node + 1]);
    int g8 = lane >> 4;          // edge subslot 0..3
    int c8 = (lane & 15) * 8;    // channel base
    float mmax = 0.f, inv = 0.f, ari = 0.f;
    if (MODE == 2) {
        ari = ar[node];
        float mm = -1e30f, ds = 0.f;
        for (int s = s0 + lane; s < end; s += 64) {
            int src = er[s] & 0xffffu;
            float e = al[src] + ari; e = e > 0.f ? e : 0.2f * e;
            if (e > mm) { ds = ds * __expf(mm - e) + 1.f; mm = e; }
            else ds += __expf(e - mm);
        }
        #pragma unroll
        for (int off = 32; off; off >>= 1) {
            float mo = __shfl_xor(mm, off);
            float dso = __shfl_xor(ds, off);
            float mn = fmaxf(mm, mo);
            ds = ds * __expf(mm - mn) + dso * __expf(mo - mn);
            mm = mn;
        }
        mmax = mm;
        inv = 1.f / ds;
    }
    float acc[8] = {0.f, 0.f, 0.f, 0.f, 0.f, 0.f, 0.f, 0.f};
    auto body = [&](int e) {
        uint_t r = er[e];
        int src = r & 0xffffu;
        float cf;
        if (MODE == 2) {
            float ev = al[src] + ari; ev = ev > 0.f ? ev : 0.2f * ev;
            cf = __expf(ev - mmax) * inv;
        } else {
            cf = hi16f(r);
        }
        uint4 u = *(const uint4*)&xw[(size_t)src * 128 + c8];
        acc[0] += cf * lo16f(u.x); acc[1] += cf * hi16f(u.x);
        acc[2] += cf * lo16f(u.y); acc[3] += cf * hi16f(u.y);
        acc[4] += cf * lo16f(u.z); acc[5] += cf * hi16f(u.z);
        acc[6] += cf * lo16f(u.w); acc[7] += cf * hi16f(u.w);
    };
    int e = s0 + g8;
    for (; e + 28 < end; e += 32) {
        body(e);      body(e + 4);  body(e + 8);  body(e + 12);
        body(e + 16); body(e + 20); body(e + 24); body(e + 28);
    }
    for (; e + 12 < end; e += 16) {
        body(e); body(e + 4); body(e + 8); body(e + 12);
    }
    for (; e < end; e += 4) body(e);
    #pragma unroll
    for (int k = 0; k < 8; ++k) {
        acc[k] += __shfl_xor(acc[k], 16);
        acc[k] += __shfl_xor(acc[k], 32);
    }
    if (g8 == 0) {
        float v[8];
        #pragma unroll
        for (int k = 0; k < 8; ++k) {
            v[k] = acc[k] + bias[c8 + k];
            if (MODE == 1) v[k] = leaky01(v[k]);
        }
        uint4 o;
        o.x = pack2(v[0], v[1]); o.y = pack2(v[2], v[3]);
        o.z = pack2(v[4], v[5]); o.w = pack2(v[6], v[7]);
        *(uint4*)&gout[(size_t)node * 128 + c8] = o;
    }
}

// ---------------- GraphNorm moments, two-stage (no global atomics) ----------------
// stage 1: per-block partials -> part[bid*256 + {ch, 128+ch}]
__global__ void moments1_k(const ushort_t* __restrict__ g, float* __restrict__ part, int n16) {
    __shared__ float s1s[256][8], s2s[256][8];
    int tid = threadIdx.x;
    long long T = (long long)gridDim.x * 256;
    float a1[8] = {0,0,0,0,0,0,0,0}, a2[8] = {0,0,0,0,0,0,0,0};
    const uint4* g4 = (const uint4*)g;
    for (long long idx = (long long)blockIdx.x * 256 + tid; idx < n16; idx += T) {
        uint4 u = g4[idx];
        float f[8] = {lo16f(u.x), hi16f(u.x), lo16f(u.y), hi16f(u.y),
                      lo16f(u.z), hi16f(u.z), lo16f(u.w), hi16f(u.w)};
        #pragma unroll
        for (int j = 0; j < 8; ++j) { a1[j] += f[j]; a2[j] += f[j] * f[j]; }
    }
    #pragma unroll
    for (int j = 0; j < 8; ++j) { s1s[tid][j] = a1[j]; s2s[tid][j] = a2[j]; }
    __syncthreads();
    // channel of (t,j) = (8t+j)&127  =>  contributors to channel c: t=(c>>3)+16k, j=c&7
    if (tid < 128) {
        int c = tid, t0 = c >> 3, j = c & 7;
        float r1 = 0.f, r2 = 0.f;
        #pragma unroll
        for (int k = 0; k < 16; ++k) {
            r1 += s1s[t0 + 16 * k][j];
            r2 += s2s[t0 + 16 * k][j];
        }
        part[(size_t)blockIdx.x * 256 + c] = r1;
        part[(size_t)blockIdx.x * 256 + 128 + c] = r2;
    }
}

// stage 2: one block reduces MOMB partial rows -> mom[0..255]
__global__ void moments2_k(const float* __restrict__ part, float* __restrict__ mom) {
    int tid = threadIdx.x;   // 256 threads, one per output word
    float s = 0.f;
    for (int b = 0; b < MOMB; ++b) s += part[(size_t)b * 256 + tid];
    mom[tid] = s;
}

// ---------------- final: x-update (not stored) + dot with Wout ----------------
__global__ void norm_ydot_k(const ushort_t* __restrict__ xb, const ushort_t* __restrict__ gb,
                            const float* __restrict__ mom,
                            const float* __restrict__ gamma, const float* __restrict__ beta,
                            const float* __restrict__ alpha, const float* __restrict__ Wout,
                            float* __restrict__ yv, int N) {
    __shared__ float sc[128], sh[128], wv[128];
    int tid = threadIdx.x;
    if (tid < 128) {
        float m = mom[tid] / (float)N;
        float a = alpha[tid];
        float var = mom[128 + tid] / (float)N - 2.f * a * m * m + a * a * m * m;
        float s = gamma[tid] * rsqrtf(var + 1e-5f);
        sc[tid] = s;
        sh[tid] = beta[tid] - s * a * m;
        wv[tid] = Wout[tid];
    }
    __syncthreads();
    int wave = tid >> 6, lane = tid & 63;
    int node = blockIdx.x * 4 + wave;
    if (node >= N) return;
    int c = lane * 2;
    uint_t gv = *(const uint_t*)&gb[(size_t)node * 128 + c];
    uint_t xv = *(const uint_t*)&xb[(size_t)node * 128 + c];
    float v0 = lo16f(xv) + leaky01(sc[c] * lo16f(gv) + sh[c]);
    float v1 = hi16f(xv) + leaky01(sc[c + 1] * hi16f(gv) + sh[c + 1]);
    float acc = v0 * wv[c] + v1 * wv[c + 1];
    #pragma unroll
    for (int off = 32; off; off >>= 1) acc += __shfl_xor(acc, off);
    if (lane == 0) yv[node] = acc;
}

// wave per node: xs = leaky( sum coef*yv[src] + b_out )
__global__ void aggs_k(const float* __restrict__ yv, const int* __restrict__ rp,
                       const uint_t* __restrict__ er,
                       const float* __restrict__ b_out, float* xs, int N) {
    int wave = threadIdx.x >> 6, lane = threadIdx.x & 63;
    int node = blockIdx.x * 4 + wave;
    if (node >= N) return;
    int s0 = rp[node], end = rp[node + 1];
    float acc = 0.f;
    for (int s = s0 + lane; s < end; s += 64) {
        uint_t r = er[s];
        acc += hi16f(r) * yv[r & 0xffffu];
    }
    #pragma unroll
    for (int off = 32; off; off >>= 1) acc += __shfl_xor(acc, off);
    if (lane == 0) xs[node] = leaky01(acc + b_out[0]);
}

__global__ void fc1_k(const float* __restrict__ xs, const float* __restrict__ W1,
                      float* hacc, int N) {
    __shared__ float sd[256];
    int tid = threadIdx.x;
    int j = tid & 127, half = tid >> 7;
    int r0 = blockIdx.x * 256;
    float acc = 0.f;
    for (int rr = half; rr < 256; rr += 2) {
        int r = r0 + rr;
        if (r < N) acc += xs[r] * W1[(size_t)r * 128 + j];
    }
    sd[tid] = acc;
    __syncthreads();
    if (tid < 128) atomicAdd(&hacc[tid], sd[tid] + sd[tid + 128]);
}

__global__ void fc2_k(const float* __restrict__ hacc, const float* __restrict__ b1,
                      const float* __restrict__ W2, const float* __restrict__ b2v,
                      float* out, int P) {
    __shared__ float hs[128];
    int tid = threadIdx.x;
    if (tid < 128) {
        float h = hacc[tid] + b1[tid];
        hs[tid] = h > 0.f ? h : 0.f;
    }
    __syncthreads();
    int p = blockIdx.x * 256 + tid;
    if (p >= P) return;
    float acc = 0.f;
    #pragma unroll 8
    for (int j = 0; j < 128; ++j) acc += hs[j] * W2[(size_t)j * P + p];
    acc += b2v[p];
    out[p] = acc > 0.f ? acc : 0.f;
}

// ---------------- launcher ----------------
extern "C" void kernel_launch(void* const* d_in, const int* in_sizes, int n_in,
                              void* d_out, int out_size, void* d_ws, size_t ws_size,
                              hipStream_t stream) {
    const int*   poi_ids  = (const int*)d_in[0];
    const int*   cat_ids  = (const int*)d_in[1];
    const float* feat3    = (const float*)d_in[2];
    const int*   ei       = (const int*)d_in[3];
    const float* ew       = (const float*)d_in[4];
    const float* poi_emb  = (const float*)d_in[5];
    const float* cat_emb  = (const float*)d_in[6];
    const float* Win      = (const float*)d_in[7];
    const float* b_in     = (const float*)d_in[8];
    const float* gcn_W    = (const float*)d_in[9];
    const float* gcn_b    = (const float*)d_in[10];
    const float* gn_gamma = (const float*)d_in[11];
    const float* gn_beta  = (const float*)d_in[12];
    const float* gn_alpha = (const float*)d_in[13];
    const float* gat_W    = (const float*)d_in[14];
    const float* gat_asrc = (const float*)d_in[15];
    const float* gat_adst = (const float*)d_in[16];
    const float* gat_b    = (const float*)d_in[17];
    const float* Wout     = (const float*)d_in[18];
    const float* b_out    = (const float*)d_in[19];
    const float* fc_W1    = (const float*)d_in[20];
    const float* fc_b1    = (const float*)d_in[21];
    const float* fc_W2    = (const float*)d_in[22];
    const float* fc_b2    = (const float*)d_in[23];

    const int N = in_sizes[0];
    const int E = in_sizes[4];
    const int POI = in_sizes[5] / 300;
    const int P = out_size;
    const int TOT = E + N;
    const int n128 = N * 128;
    const int n16 = n128 / 8;
    const int NPAD = ((N + 63) / 64) * 64;
    const int PPAD = ((POI + 63) / 64) * 64;

    // workspace carve (256B aligned)
    char* w = (char*)d_ws;
    size_t off = 0;
    auto take = [&](size_t bytes) -> char* {
        char* p = w + off;
        off = (off + bytes + 255) & ~(size_t)255;
        return p;
    };
    ushort_t* xb   = (ushort_t*)take((size_t)NPAD * 128 * 2);
    ushort_t* g    = (ushort_t*)take((size_t)NPAD * 128 * 2);
    ushort_t* xw   = (ushort_t*)take((size_t)NPAD * 128 * 2);
    ushort_t* pp   = (ushort_t*)take((size_t)PPAD * 128 * 2);
    float*    cp   = (float*)take((size_t)400 * 128 * 4);
    ushort_t* wt   = (ushort_t*)take((size_t)10 * 16384 * 2);
    ushort_t* wtin = (ushort_t*)take((size_t)128 * 320 * 2);
    int*    rp   = (int*)take((size_t)(N + 1) * 4);
    int*    cnt  = (int*)take((size_t)N * 4);
    int*    pos  = (int*)take((size_t)E * 4);
    float*  dinv = (float*)take((size_t)N * 4);
    uint_t* er   = (uint_t*)take((size_t)TOT * 4);
    float*  al   = (float*)take((size_t)N * 4);
    float*  ar   = (float*)take((size_t)N * 4);
    float*  yv   = (float*)take((size_t)N * 4);
    float*  xs   = (float*)take((size_t)N * 4);
    float*  part = (float*)take((size_t)MOMB * 256 * 4);
    float*  mom  = (float*)take((size_t)(10 * 256 + 128) * 4);
    float*  hacc = mom + 10 * 256;

    const int gN   = (N + 255) / 256;
    const int gE   = (E + 255) / 256;
    const int gMM  = NPAD / 64;
    const int gPOI = PPAD / 64;
    const int gW   = (N + 3) / 4;
    const int gP   = (P + 255) / 256;

    hipMemsetAsync(hacc, 0, 128 * 4, stream);

    // CSR build
    init_k<<<gN, 256, 0, stream>>>(cnt, N);
    count_k<<<gE, 256, 0, stream>>>(ei, cnt, pos, E);
    scan_k<<<1, 1024, 0, stream>>>(cnt, rp, N);
    post_k<<<gN, 256, 0, stream>>>(rp, er, N);
    scat_k<<<gE, 256, 0, stream>>>(ei, ew, rp, pos, er, E);
    deg_k<<<gW, 256, 0, stream>>>(rp, er, dinv, N);
    coef_k<<<gW, 256, 0, stream>>>(rp, er, dinv, N);

    // weight prep + input conv
    prep_w<<<(10 * 16384 + 128 * 320 + 255) / 256, 256, 0, stream>>>(gcn_W, gat_W, Win, wt, wtin);
    cat_proj_k<<<400, 128, 0, stream>>>(cat_emb, Win, cp);
    poi_gemm<<<gPOI, 256, 0, stream>>>(poi_emb, wtin, pp, POI);
    combine_k<<<(N + 1) / 2, 256, 0, stream>>>(pp, cp, poi_ids, cat_ids, feat3, Win, xw, N);
    agg_k<1><<<gW, 256, 0, stream>>>(xw, rp, er, nullptr, nullptr, b_in, xb, N);

    // 5 GcnUnits
    for (int l = 0; l < 5; ++l) {
        // GCN half: gemm (fused norm of previous GAT half for l>=1)
        if (l == 0)
            gemm_fused<0, 0><<<gMM, 256, 0, stream>>>(xb, nullptr, nullptr, nullptr, nullptr,
                                                      nullptr, wt, nullptr, nullptr,
                                                      xw, nullptr, nullptr, N);
        else
            gemm_fused<1, 0><<<gMM, 256, 0, stream>>>(xb, g, mom + (2 * l - 1) * 256,
                                                      gn_gamma + (l - 1) * 128,
                                                      gn_beta + (l - 1) * 128,
                                                      gn_alpha + (l - 1) * 128,
                                                      wt + (size_t)l * 16384, nullptr, nullptr,
                                                      xw, nullptr, nullptr, N);
        agg_k<0><<<gW, 256, 0, stream>>>(xw, rp, er, nullptr, nullptr, gcn_b + l * 128, g, N);
        moments1_k<<<MOMB, 256, 0, stream>>>(g, part, n16);
        moments2_k<<<1, 256, 0, stream>>>(part, mom + (2 * l) * 256);

        // GAT half: gemm with fused norm (this unit's GCN) + alar epilogue
        gemm_fused<1, 1><<<gMM, 256, 0, stream>>>(xb, g, mom + (2 * l) * 256,
                                                  gn_gamma + l * 128, gn_beta + l * 128,
                                                  gn_alpha + l * 128,
                                                  wt + (size_t)(5 + l) * 16384,
                                                  gat_asrc + l * 128, gat_adst + l * 128,
                                                  xw, al, ar, N);
        agg_k<2><<<gW, 256, 0, stream>>>(xw, rp, er, al, ar, gat_b + l * 128, g, N);
        moments1_k<<<MOMB, 256, 0, stream>>>(g, part, n16);
        moments2_k<<<1, 256, 0, stream>>>(part, mom + (2 * l + 1) * 256);
    }

    // final norm + output conv (C -> 1) + leaky
    norm_ydot_k<<<gW, 256, 0, stream>>>(xb, g, mom + 9 * 256, gn_gamma + 4 * 128,
                                        gn_beta + 4 * 128, gn_alpha + 4 * 128, Wout, yv, N);
    aggs_k<<<gW, 256, 0, stream>>>(yv, rp, er, b_out, xs, N);

    // FC head
    fc1_k<<<(N + 255) / 256, 256, 0, stream>>>(xs, fc_W1, hacc, N);
    fc2_k<<<gP, 256, 0, stream>>>(hacc, fc_b1, fc_W2, fc_b2, (float*)d_out, P);
}